// Round 5
// baseline (217.099 us; speedup 1.0000x reference)
//
#include <hip/hip_runtime.h>
#include <hip/hip_cooperative_groups.h>

namespace cg = cooperative_groups;

#define SEQ  200
#define DIM  512
#define NBLK 1024   // one block per batch row; exactly fills 256 CUs at 4 blk/CU

// Fused cooperative kernel, full occupancy (1024 blk x 512 thr = 8192 waves).
// Phase 1: stage idx+freq for this row, accumulate ssq partial (grid covers
//          xs exactly once) -> atomicAdd(double).
// Phase 2: UNNORMALIZED gather-pool (inv_norm commutes out of the sum).
//          4 groups x 128 lanes; each lane owns a float4 slice; unroll 8 to
//          maximize outstanding loads per wave (MLP is the limiter).
// Phase 3: grid.sync, scale by 1/sqrt(ssq), write.
__global__ __launch_bounds__(512, 8) void fused_kernel(
        const int* __restrict__ xs,
        const float* __restrict__ W,
        const float* __restrict__ freqs,
        double* __restrict__ ssq,
        float* __restrict__ out) {
    __shared__ int    s_idx[SEQ];
    __shared__ float  s_f[SEQ];
    __shared__ float  s_part[3][DIM];
    __shared__ double s_w[8];
    __shared__ float  s_inv;

    const int b       = blockIdx.x;
    const int tid     = threadIdx.x;
    const int group   = tid >> 7;     // 0..3
    const int lane128 = tid & 127;
    const int col4    = lane128 * 4;

    // ---- Phase 1: stage + ssq partial ----
    float ssl = 0.f;
    for (int l = tid; l < SEQ; l += 512) {
        int   idx = xs[(size_t)b * SEQ + l];
        float f   = freqs[idx];
        s_idx[l] = idx;
        s_f[l]   = f;
        ssl += f * f;
    }
    double accd = (double)ssl;
    for (int off = 32; off > 0; off >>= 1)
        accd += __shfl_down(accd, off, 64);
    if ((tid & 63) == 0) s_w[tid >> 6] = accd;
    __syncthreads();
    if (tid == 0) {
        double t = 0.0;
        for (int w = 0; w < 8; ++w) t += s_w[w];
        atomicAdd(ssq, t);
    }
    // s_idx/s_f are ready (the __syncthreads above covers the stage loop)

    // ---- Phase 2: unnormalized pool, high-MLP ----
    float4 acc = make_float4(0.f, 0.f, 0.f, 0.f);
    #pragma unroll 8
    for (int l = group; l < SEQ; l += 4) {
        const int   idx = s_idx[l];
        const float s   = s_f[l];
        const float4 w  = *reinterpret_cast<const float4*>(
            W + (size_t)idx * DIM + col4);
        acc.x += s * w.x;
        acc.y += s * w.y;
        acc.z += s * w.z;
        acc.w += s * w.w;
    }
    if (group > 0)
        *reinterpret_cast<float4*>(&s_part[group - 1][col4]) = acc;
    __syncthreads();
    if (group == 0) {
        for (int g = 0; g < 3; ++g) {
            const float4 p = *reinterpret_cast<const float4*>(&s_part[g][col4]);
            acc.x += p.x; acc.y += p.y; acc.z += p.z; acc.w += p.w;
        }
    }

    // ---- Phase 3: global norm, scale, write ----
    cg::this_grid().sync();
    if (tid == 0) {
        double v = __hip_atomic_load(ssq, __ATOMIC_ACQUIRE,
                                     __HIP_MEMORY_SCOPE_AGENT);
        s_inv = (float)(1.0 / sqrt(v));
    }
    __syncthreads();
    if (group == 0) {
        const float inv = s_inv;
        float4 o = acc;
        o.x *= inv; o.y *= inv; o.z *= inv; o.w *= inv;
        *reinterpret_cast<float4*>(out + (size_t)b * DIM + col4) = o;
    }
}

// ---------------- Fallback (non-cooperative) path ----------------------------
__global__ __launch_bounds__(256) void ssq_kernel(const int* __restrict__ xs,
                                                  const float* __restrict__ freqs,
                                                  double* __restrict__ ssq,
                                                  int n) {
    double acc = 0.0;
    for (int i = blockIdx.x * blockDim.x + threadIdx.x; i < n;
         i += gridDim.x * blockDim.x) {
        float f = freqs[xs[i]];
        acc += (double)f * (double)f;
    }
    for (int off = 32; off > 0; off >>= 1)
        acc += __shfl_down(acc, off, 64);
    __shared__ double s_w[4];
    if ((threadIdx.x & 63) == 0) s_w[threadIdx.x >> 6] = acc;
    __syncthreads();
    if (threadIdx.x == 0)
        atomicAdd(ssq, s_w[0] + s_w[1] + s_w[2] + s_w[3]);
}

__global__ __launch_bounds__(512) void pool_kernel(const int* __restrict__ xs,
                                                   const float* __restrict__ W,
                                                   const float* __restrict__ freqs,
                                                   const double* __restrict__ ssq,
                                                   float* __restrict__ out) {
    __shared__ int   s_idx[SEQ];
    __shared__ float s_scl[SEQ];
    __shared__ float s_part[3][DIM];
    const int b   = blockIdx.x;
    const int tid = threadIdx.x;
    const float inv_norm = (float)(1.0 / sqrt(ssq[0]));
    for (int l = tid; l < SEQ; l += 512) {
        int idx  = xs[(size_t)b * SEQ + l];
        s_idx[l] = idx;
        s_scl[l] = freqs[idx] * inv_norm;
    }
    __syncthreads();
    const int group = tid >> 7, lane128 = tid & 127, col4 = lane128 * 4;
    float4 acc = make_float4(0.f, 0.f, 0.f, 0.f);
    #pragma unroll 8
    for (int l = group; l < SEQ; l += 4) {
        const int   idx = s_idx[l];
        const float s   = s_scl[l];
        const float4 w  = *reinterpret_cast<const float4*>(
            W + (size_t)idx * DIM + col4);
        acc.x += s * w.x; acc.y += s * w.y; acc.z += s * w.z; acc.w += s * w.w;
    }
    if (group > 0)
        *reinterpret_cast<float4*>(&s_part[group - 1][col4]) = acc;
    __syncthreads();
    if (group == 0) {
        for (int g = 0; g < 3; ++g) {
            const float4 p = *reinterpret_cast<const float4*>(&s_part[g][col4]);
            acc.x += p.x; acc.y += p.y; acc.z += p.z; acc.w += p.w;
        }
        *reinterpret_cast<float4*>(out + (size_t)b * DIM + col4) = acc;
    }
}

extern "C" void kernel_launch(void* const* d_in, const int* in_sizes, int n_in,
                              void* d_out, int out_size, void* d_ws, size_t ws_size,
                              hipStream_t stream) {
    const int*   xs    = (const int*)d_in[0];    // [1024, 200] int32
    const float* W     = (const float*)d_in[1];  // [100000, 512] f32
    const float* freqs = (const float*)d_in[2];  // [100000] f32
    float*  out = (float*)d_out;                 // [1024, 512] f32
    double* ssq = (double*)d_ws;

    const int n   = in_sizes[0];   // 204800
    const int bsz = n / SEQ;       // 1024

    hipMemsetAsync(d_ws, 0, sizeof(double), stream);

    void* args[] = {(void*)&xs, (void*)&W, (void*)&freqs,
                    (void*)&ssq, (void*)&out};
    hipError_t e = hipLaunchCooperativeKernel((const void*)fused_kernel,
                                              dim3(NBLK), dim3(512),
                                              args, 0, stream);
    if (e != hipSuccess) {
        (void)hipGetLastError();  // clear, take the 2-kernel path
        ssq_kernel<<<400, 256, 0, stream>>>(xs, freqs, ssq, n);
        pool_kernel<<<bsz, 512, 0, stream>>>(xs, W, freqs, ssq, out);
    }
}

// Round 6
// 68.479 us; speedup vs baseline: 3.1703x; 3.1703x over previous
//
#include <hip/hip_runtime.h>

#define SEQ        200
#define DIM        512
#define SSQ_BLOCKS 256

// ---------------- Kernel A: ssq partials (atomic-free, no init needed) ------
__global__ __launch_bounds__(256) void ssq_partial(const int* __restrict__ xs,
                                                   const float* __restrict__ freqs,
                                                   double* __restrict__ partials,
                                                   int n) {
    float acc = 0.f;
    for (int i = blockIdx.x * 256 + threadIdx.x; i < n; i += SSQ_BLOCKS * 256) {
        float f = freqs[xs[i]];
        acc += f * f;
    }
    double accd = (double)acc;
    for (int off = 32; off > 0; off >>= 1)
        accd += __shfl_down(accd, off, 64);
    __shared__ double s_w[4];
    if ((threadIdx.x & 63) == 0) s_w[threadIdx.x >> 6] = accd;
    __syncthreads();
    if (threadIdx.x == 0)
        partials[blockIdx.x] = s_w[0] + s_w[1] + s_w[2] + s_w[3];  // overwrite
}

// ---------------- Kernel B: gather-pool, depth-5 pipelined -------------------
// 1024 blocks x 512 threads (R1 geometry: the fastest measured). Each block:
//  (1) reduce the 256 ssq partials -> inv_norm (cheap, L2-hot),
//  (2) stage idx + scaled freq in LDS,
//  (3) gather loop with 5 loads batched per chunk -> per-wave MLP >= 5.
__global__ __launch_bounds__(512) void pool_kernel(const int* __restrict__ xs,
                                                   const float* __restrict__ W,
                                                   const float* __restrict__ freqs,
                                                   const double* __restrict__ partials,
                                                   float* __restrict__ out) {
    __shared__ int    s_idx[SEQ];
    __shared__ float  s_scl[SEQ];
    __shared__ float  s_part[3][DIM];
    __shared__ double s_w[8];
    __shared__ float  s_inv;

    const int b   = blockIdx.x;
    const int tid = threadIdx.x;

    // ---- (1) reduce partials -> inv_norm ----
    double v = (tid < SSQ_BLOCKS) ? partials[tid] : 0.0;
    for (int off = 32; off > 0; off >>= 1)
        v += __shfl_down(v, off, 64);
    if ((tid & 63) == 0) s_w[tid >> 6] = v;
    __syncthreads();
    if (tid == 0) {
        double t = 0.0;
        for (int w = 0; w < 8; ++w) t += s_w[w];
        s_inv = (float)(1.0 / sqrt(t));
    }
    __syncthreads();
    const float inv_norm = s_inv;

    // ---- (2) stage indices + scales ----
    for (int l = tid; l < SEQ; l += 512) {
        int idx  = xs[(size_t)b * SEQ + l];
        s_idx[l] = idx;
        s_scl[l] = freqs[idx] * inv_norm;
    }
    __syncthreads();

    // ---- (3) pipelined gather-pool ----
    const int group   = tid >> 7;     // 0..3
    const int lane128 = tid & 127;
    const int col4    = lane128 * 4;

    float4 acc = make_float4(0.f, 0.f, 0.f, 0.f);

    // per-group trip count = SEQ/4 = 50 = 10 chunks x 5
    #pragma unroll 1
    for (int c = 0; c < SEQ / 4; c += 5) {
        float4 wv[5];
        float  sv[5];
        #pragma unroll
        for (int k = 0; k < 5; ++k) {
            const int l = group + 4 * (c + k);
            const int idx = s_idx[l];
            sv[k] = s_scl[l];
            wv[k] = *reinterpret_cast<const float4*>(
                W + (size_t)idx * DIM + col4);
        }
        #pragma unroll
        for (int k = 0; k < 5; ++k) {
            acc.x += sv[k] * wv[k].x;
            acc.y += sv[k] * wv[k].y;
            acc.z += sv[k] * wv[k].z;
            acc.w += sv[k] * wv[k].w;
        }
    }

    if (group > 0)
        *reinterpret_cast<float4*>(&s_part[group - 1][col4]) = acc;
    __syncthreads();
    if (group == 0) {
        for (int g = 0; g < 3; ++g) {
            const float4 p = *reinterpret_cast<const float4*>(&s_part[g][col4]);
            acc.x += p.x; acc.y += p.y; acc.z += p.z; acc.w += p.w;
        }
        *reinterpret_cast<float4*>(out + (size_t)b * DIM + col4) = acc;
    }
}

extern "C" void kernel_launch(void* const* d_in, const int* in_sizes, int n_in,
                              void* d_out, int out_size, void* d_ws, size_t ws_size,
                              hipStream_t stream) {
    const int*   xs    = (const int*)d_in[0];    // [1024, 200] int32
    const float* W     = (const float*)d_in[1];  // [100000, 512] f32
    const float* freqs = (const float*)d_in[2];  // [100000] f32
    float*  out      = (float*)d_out;            // [1024, 512] f32
    double* partials = (double*)d_ws;            // 256 doubles

    const int n   = in_sizes[0];   // 204800
    const int bsz = n / SEQ;       // 1024

    ssq_partial<<<SSQ_BLOCKS, 256, 0, stream>>>(xs, freqs, partials, n);
    pool_kernel<<<bsz, 512, 0, stream>>>(xs, W, freqs, partials, out);
}

// Round 7
// 67.516 us; speedup vs baseline: 3.2155x; 1.0143x over previous
//
#include <hip/hip_runtime.h>

#define SEQ  200
#define DIM  512
#define BSZ_BLOCKS 1024
#define RS_BLOCKS  256

// ---------------- Kernel A: unnormalized gather-pool + per-row ssq ----------
// 1024 blocks x 512 threads. Stage idx+freq in LDS (freq values double as the
// ssq contribution - zero extra traffic), gather depth-10 pipelined,
// accumulate UNNORMALIZED (global inv_norm commutes out), write out + the
// per-row ssq partial. No dependency on any prior kernel.
__global__ __launch_bounds__(512) void pool_kernel(const int* __restrict__ xs,
                                                   const float* __restrict__ W,
                                                   const float* __restrict__ freqs,
                                                   double* __restrict__ partials,
                                                   float* __restrict__ out) {
    __shared__ int    s_idx[SEQ];
    __shared__ float  s_f[SEQ];
    __shared__ float  s_part[3][DIM];
    __shared__ double s_w[8];

    const int b   = blockIdx.x;
    const int tid = threadIdx.x;

    // ---- stage indices + freqs, accumulate local ssq ----
    float ssl = 0.f;
    for (int l = tid; l < SEQ; l += 512) {
        int   idx = xs[(size_t)b * SEQ + l];
        float f   = freqs[idx];
        s_idx[l] = idx;
        s_f[l]   = f;
        ssl += f * f;
    }
    double accd = (double)ssl;
    for (int off = 32; off > 0; off >>= 1)
        accd += __shfl_down(accd, off, 64);
    if ((tid & 63) == 0) s_w[tid >> 6] = accd;
    __syncthreads();          // covers stage loop AND s_w
    if (tid == 0) {
        double t = 0.0;
        for (int w = 0; w < 8; ++w) t += s_w[w];
        partials[b] = t;      // overwrite, no init needed
    }

    // ---- depth-10 pipelined unnormalized gather-pool ----
    const int group   = tid >> 7;     // 0..3
    const int lane128 = tid & 127;
    const int col4    = lane128 * 4;

    float4 acc = make_float4(0.f, 0.f, 0.f, 0.f);

    // per-group trips = SEQ/4 = 50 = 5 chunks x 10
    #pragma unroll 1
    for (int c = 0; c < SEQ / 4; c += 10) {
        float4 wv[10];
        float  sv[10];
        #pragma unroll
        for (int k = 0; k < 10; ++k) {
            const int l   = group + 4 * (c + k);
            const int idx = s_idx[l];
            sv[k] = s_f[l];
            wv[k] = *reinterpret_cast<const float4*>(
                W + (size_t)idx * DIM + col4);
        }
        #pragma unroll
        for (int k = 0; k < 10; ++k) {
            acc.x += sv[k] * wv[k].x;
            acc.y += sv[k] * wv[k].y;
            acc.z += sv[k] * wv[k].z;
            acc.w += sv[k] * wv[k].w;
        }
    }

    if (group > 0)
        *reinterpret_cast<float4*>(&s_part[group - 1][col4]) = acc;
    __syncthreads();
    if (group == 0) {
        for (int g = 0; g < 3; ++g) {
            const float4 p = *reinterpret_cast<const float4*>(&s_part[g][col4]);
            acc.x += p.x; acc.y += p.y; acc.z += p.z; acc.w += p.w;
        }
        *reinterpret_cast<float4*>(out + (size_t)b * DIM + col4) = acc;  // unnormalized
    }
}

// ---------------- Kernel B: reduce partials + in-place rescale ---------------
// 256 blocks x 256 threads. Each block redundantly reduces the 1024 doubles
// (8 KB, L2-hot) -> inv_norm, then rescales its 2048-float slice of out.
__global__ __launch_bounds__(256) void rescale_kernel(const double* __restrict__ partials,
                                                      float* __restrict__ out) {
    __shared__ double s_w[4];
    __shared__ float  s_inv;

    const int tid = threadIdx.x;

    double v = 0.0;
    #pragma unroll
    for (int k = 0; k < BSZ_BLOCKS / 256; ++k)   // 4 doubles/thread
        v += partials[tid + 256 * k];
    for (int off = 32; off > 0; off >>= 1)
        v += __shfl_down(v, off, 64);
    if ((tid & 63) == 0) s_w[tid >> 6] = v;
    __syncthreads();
    if (tid == 0) {
        double t = s_w[0] + s_w[1] + s_w[2] + s_w[3];
        s_inv = (float)(1.0 / sqrt(t));
    }
    __syncthreads();
    const float inv = s_inv;

    // rescale: total 1024*512 floats = 131072 float4; 256 blk x 256 thr -> 2 each
    const int base = (blockIdx.x * 256 + tid) * 2;   // float4 index
    float4* o4 = reinterpret_cast<float4*>(out);
    #pragma unroll
    for (int k = 0; k < 2; ++k) {
        float4 o = o4[base + k];
        o.x *= inv; o.y *= inv; o.z *= inv; o.w *= inv;
        o4[base + k] = o;
    }
}

extern "C" void kernel_launch(void* const* d_in, const int* in_sizes, int n_in,
                              void* d_out, int out_size, void* d_ws, size_t ws_size,
                              hipStream_t stream) {
    const int*   xs    = (const int*)d_in[0];    // [1024, 200] int32
    const float* W     = (const float*)d_in[1];  // [100000, 512] f32
    const float* freqs = (const float*)d_in[2];  // [100000] f32
    float*  out      = (float*)d_out;            // [1024, 512] f32
    double* partials = (double*)d_ws;            // 1024 doubles

    const int n   = in_sizes[0];   // 204800
    const int bsz = n / SEQ;       // 1024

    pool_kernel<<<bsz, 512, 0, stream>>>(xs, W, freqs, partials, out);
    rescale_kernel<<<RS_BLOCKS, 256, 0, stream>>>(partials, out);
}